// Round 1
// baseline (100.823 us; speedup 1.0000x reference)
//
#include <hip/hip_runtime.h>

#define HH 512
#define WW 512
#define BB 4
#define TILE 16
#define HALO 5
#define LT (TILE + 2 * HALO) /* 26 */
#define PI_F 3.14159265358979323846f

// Depth-aware scatter (splat) bokeh rendered as gather.
// out[b,c,y,x] = sum_{(di,dj) in disk} [r(src) >= dist(di,dj)] * g(src) * rgb(src,c)
//             / sum_{(di,dj) in disk} [r(src) >= dist(di,dj)] * g(src)
// src = (clamp(y+di-5), clamp(x+dj-5)); r = min(|disp|*lens_b, 5); g = 1/(pi r^2 + 1).
__global__ __launch_bounds__(256) void Scatter_Rendering_87101936763449_kernel(
    const float* __restrict__ x, const float* __restrict__ lens,
    const float* __restrict__ dk, float* __restrict__ out) {
    __shared__ float4 sg[LT * LT]; // (s0, s1, s2, g) per staged pixel
    __shared__ float  sr[LT * LT]; // r per staged pixel

    const int b  = blockIdx.z;
    const int bx = blockIdx.x * TILE;
    const int by = blockIdx.y * TILE;
    const int t  = threadIdx.x;

    const float le = lens[b]; // uniform scalar
    const float* xb = x + (size_t)b * 4 * HH * WW;

    // Stage 26x26 halo'd tile: compute r, g once per source pixel.
    for (int i = t; i < LT * LT; i += 256) {
        int ly = i / LT, lx = i - ly * LT;
        int gy = by + ly - HALO; gy = gy < 0 ? 0 : (gy > HH - 1 ? HH - 1 : gy);
        int gx = bx + lx - HALO; gx = gx < 0 ? 0 : (gx > WW - 1 ? WW - 1 : gx);
        int gi = gy * WW + gx;
        float d  = xb[3 * HH * WW + gi];
        float r  = fminf(fabsf(d) * le, (float)HALO);
        float pr = PI_F * r;
        float g  = 1.0f / (pr * r + 1.0f);
        sr[i] = r;
        sg[i] = make_float4(xb[gi] * g, xb[HH * WW + gi] * g, xb[2 * HH * WW + gi] * g, g);
    }

    // Preload the 14 distinct dist values from the INPUT diskernel (exact
    // same floats the reference compares against). Static indices -> SGPRs.
    float distv[26];
#pragma unroll
    for (int a = 0; a <= 5; ++a) {
#pragma unroll
        for (int c = a; c <= 5; ++c) {
            int d2 = a * a + c * c;
            if (d2 <= 25) distv[d2] = dk[(5 + a) * 11 + (5 + c)];
        }
    }

    __syncthreads();

    const int tx = t & (TILE - 1);
    const int ty = t >> 4;
    const int base = ty * LT + tx;

    float n0 = 0.f, n1 = 0.f, n2 = 0.f, den = 0.f;
#pragma unroll
    for (int di = 0; di < 11; ++di) {
#pragma unroll
        for (int dj = 0; dj < 11; ++dj) {
            const int d2 = (di - 5) * (di - 5) + (dj - 5) * (dj - 5);
            if (d2 > 25) continue; // lens_mask == 0 here (dist > 5), compile-time skip
            const float dist = distv[d2];
            const int idx = base + di * LT + dj; // constant offset folds into ds_read imm
            float  r = sr[idx];
            float4 v = sg[idx];
            float wm = (r >= dist) ? 1.0f : 0.0f; // mask==1 on all kept offsets
            n0  = fmaf(wm, v.x, n0);
            n1  = fmaf(wm, v.y, n1);
            n2  = fmaf(wm, v.z, n2);
            den = fmaf(wm, v.w, den);
        }
    }

    const float inv = 1.0f / den;
    const size_t o = (size_t)b * 3 * HH * WW + (size_t)(by + ty) * WW + (bx + tx);
    out[o]               = n0 * inv;
    out[o + HH * WW]     = n1 * inv;
    out[o + 2 * HH * WW] = n2 * inv;
}

extern "C" void kernel_launch(void* const* d_in, const int* in_sizes, int n_in,
                              void* d_out, int out_size, void* d_ws, size_t ws_size,
                              hipStream_t stream) {
    const float* x    = (const float*)d_in[0]; // (4,4,512,512)
    const float* lens = (const float*)d_in[1]; // (4,1)
    const float* dk   = (const float*)d_in[2]; // (11,11) distance kernel
    // d_in[3] (lens_mask) is deterministic (dist<=5) and baked at compile time.
    float* out = (float*)d_out;                // (4,3,512,512)

    dim3 grid(WW / TILE, HH / TILE, BB);
    dim3 block(256);
    hipLaunchKernelGGL(Scatter_Rendering_87101936763449_kernel, grid, block, 0, stream,
                       x, lens, dk, out);
}